// Round 12
// baseline (823.888 us; speedup 1.0000x reference)
//
#include <hip/hip_runtime.h>

typedef short bf16x8 __attribute__((ext_vector_type(8)));
typedef _Float16 f16x8 __attribute__((ext_vector_type(8)));
typedef float f32x4 __attribute__((ext_vector_type(4)));
typedef float f32x16 __attribute__((ext_vector_type(16)));

__device__ __forceinline__ short f2h(float f) {
  _Float16 h = (_Float16)f;
  return __builtin_bit_cast(short, h);
}
__device__ __forceinline__ float h2f(short s) {
  return (float)__builtin_bit_cast(_Float16, s);
}

__device__ __forceinline__ void gload16(const void* g, void* lds) {
  __builtin_amdgcn_global_load_lds(
      (const __attribute__((address_space(1))) unsigned*)g,
      (__attribute__((address_space(3))) unsigned*)lds, 16, 0, 0);
}

// ---------------------------------------------------------------------------
// Fat-wave 256x256 GEMM on mfma_f32_32x32x16_f16. C = A @ B^T (f16, K
// contiguous). 256 thr = 4 waves, wave grid 2Mx2N, wave tile 128x128 =
// 4x4 frags of 32x32 (acc f32x16[4][4]). 32x32x16 retires 32768 FLOP/8.07cyc
// vs 16x16x32's 16384/4.85 -> per-chunk MFMA issue floor halves (4966->2066
// cyc); rounds 6/8/11 all measured ~93% of the 16x16 floor, so the shape was
// the wall, not the schedule. LDS image/staging/swizzle identical to r11
// (measured 0 conflicts). Chunk=K=64: A 256x128B + B, 2 slots, vmcnt(16)
// counted prefetch. Reads: 32 b128/wave (ks0..3); lgkm(15) [in-order DS ->
// ks0+ks1 resident] -> 32 MFMA -> lgkm(0) -> 32 MFMA.
// Frag layout 32x32x16: A/B row(col)=lane&31, k=8*(lane>>5)+j;
// C/D col=lane&31, row=(r&3)+8*(r>>2)+4*(lane>>5)  [guide m101].
// ---------------------------------------------------------------------------
template <int K, int OMODE, int BIAS_MODE, int RES>
__global__ __launch_bounds__(256, 1) void gemm32(
    const short* __restrict__ A, int lda, long sA,
    const short* __restrict__ B, int ldb, long sB,
    void* __restrict__ Cv, int ldc, long sC,
    const float* __restrict__ bias, const float* __restrict__ resid, long sR) {
  constexpr int NT = K / 64;
  __shared__ __align__(1024) char lds[131072];  // 2 x (A 32KB + B 32KB)

  A += (size_t)blockIdx.z * sA;
  B += (size_t)blockIdx.z * sB;
  char* Cb = (char*)Cv + (size_t)blockIdx.z * sC * (OMODE == 0 ? 4 : 2);
  const float* res = resid ? resid + (size_t)blockIdx.z * sR : nullptr;

  const int tid = threadIdx.x;
  const int wid = tid >> 6, lane = tid & 63;
  const int wm = wid >> 1, wn = wid & 1;  // wave grid 2 (M) x 2 (N)
  const int l31 = lane & 31, hl = lane >> 5;
  const size_t bm = (size_t)blockIdx.y * 256;
  const size_t bn = (size_t)blockIdx.x * 256;

  const char* Ag = (const char*)A;
  const char* Bg = (const char*)B;
  const size_t ldaB = (size_t)lda * 2, ldbB = (size_t)ldb * 2;

  // staging (identical to r11): gload i covers rows 32i + wid*8 + (lane>>3);
  // col granule (lane&7)^(lane>>3) (inv-swizzle), linear LDS dest.
  const int lrow = lane >> 3;
  const int scol = ((lane & 7) ^ lrow) * 16;

  // ds_read offsets: row = w*128 + l31 (+m*32 -> +m*4096B), row&7 = lane&7;
  // byte-in-row = (ks*2+hl)*16, swizzled ^(row&7)<<4.
  int aoff[4], boff[4];
#pragma unroll
  for (int ks = 0; ks < 4; ks++) {
    const int byt = ((ks * 2 + hl) * 16) ^ ((lane & 7) << 4);
    aoff[ks] = (wm * 128 + l31) * 128 + byt;
    boff[ks] = 32768 + (wn * 128 + l31) * 128 + byt;
  }

  f32x16 acc[4][4];
#pragma unroll
  for (int m = 0; m < 4; m++)
#pragma unroll
    for (int n = 0; n < 4; n++)
#pragma unroll
      for (int r = 0; r < 16; r++) acc[m][n][r] = 0.f;

  auto stage = [&](int t) {
    char* s = &lds[(t & 1) * 65536];
    const size_t ktB = (size_t)t * 128;
#pragma unroll
    for (int i = 0; i < 8; ++i)
      gload16(Ag + (bm + 32 * i + wid * 8 + lrow) * ldaB + ktB + scol,
              s + i * 4096 + wid * 1024);
#pragma unroll
    for (int i = 0; i < 8; ++i)
      gload16(Bg + (bn + 32 * i + wid * 8 + lrow) * ldbB + ktB + scol,
              s + 32768 + i * 4096 + wid * 1024);
  };

  stage(0);
  for (int t = 0; t < NT; ++t) {
    __builtin_amdgcn_s_barrier();
    __builtin_amdgcn_sched_barrier(0);
    if (t + 1 < NT) {
      stage(t + 1);
      __builtin_amdgcn_sched_barrier(0);
      asm volatile("s_waitcnt vmcnt(16)");
    } else {
      asm volatile("s_waitcnt vmcnt(0)");
    }
    __builtin_amdgcn_sched_barrier(0);
    const char* s = &lds[(t & 1) * 65536];
    f16x8 a[4][4], b[4][4];  // [ks][frag]
#pragma unroll
    for (int ks = 0; ks < 4; ks++) {
#pragma unroll
      for (int m = 0; m < 4; m++)
        a[ks][m] = *(const f16x8*)(s + (aoff[ks] + m * 4096));
#pragma unroll
      for (int n = 0; n < 4; n++)
        b[ks][n] = *(const f16x8*)(s + (boff[ks] + n * 4096));
    }
    __builtin_amdgcn_sched_barrier(0);
    asm volatile("s_waitcnt lgkmcnt(15)");  // in-order DS: ks0+ks1 resident
    __builtin_amdgcn_sched_barrier(0);
    __builtin_amdgcn_s_setprio(1);
#pragma unroll
    for (int ks = 0; ks < 2; ks++)
#pragma unroll
      for (int m = 0; m < 4; m++)
#pragma unroll
        for (int n = 0; n < 4; n++)
          acc[m][n] = __builtin_amdgcn_mfma_f32_32x32x16_f16(
              a[ks][m], b[ks][n], acc[m][n], 0, 0, 0);
    __builtin_amdgcn_s_setprio(0);
    __builtin_amdgcn_sched_barrier(0);
    asm volatile("s_waitcnt lgkmcnt(0)");
    __builtin_amdgcn_sched_barrier(0);
    __builtin_amdgcn_s_setprio(1);
#pragma unroll
    for (int ks = 2; ks < 4; ks++)
#pragma unroll
      for (int m = 0; m < 4; m++)
#pragma unroll
        for (int n = 0; n < 4; n++)
          acc[m][n] = __builtin_amdgcn_mfma_f32_32x32x16_f16(
              a[ks][m], b[ks][n], acc[m][n], 0, 0, 0);
    __builtin_amdgcn_s_setprio(0);
    __builtin_amdgcn_sched_barrier(0);
  }

#pragma unroll
  for (int m = 0; m < 4; m++) {
    const size_t row0 = bm + wm * 128 + m * 32 + 4 * hl;
#pragma unroll
    for (int n = 0; n < 4; n++) {
      const size_t col = bn + wn * 128 + n * 32 + l31;
      float bcol = (BIAS_MODE == 1) ? bias[col] : 0.f;
#pragma unroll
      for (int r = 0; r < 16; r++) {
        float val = acc[m][n][r];
        const size_t row = row0 + (r & 3) + 8 * (r >> 2);
        const size_t idx = row * (size_t)ldc + col;
        if (BIAS_MODE == 1) val += bcol;
        if (BIAS_MODE == 2) val += bias[row];
        if (RES) val += res[idx];
        if (OMODE == 0)
          ((float*)Cb)[idx] = val;
        else
          ((short*)Cb)[idx] = f2h(val);
      }
    }
  }
}

__global__ __launch_bounds__(256) void cvt_f32_f16(const float* __restrict__ s,
                                                   short* __restrict__ d, int n) {
  int i = (blockIdx.x * 256 + threadIdx.x) * 8;
  if (i >= n) return;
  const float4 a = *(const float4*)(s + i);
  const float4 b = *(const float4*)(s + i + 4);
  bf16x8 o;
  o[0] = f2h(a.x); o[1] = f2h(a.y); o[2] = f2h(a.z); o[3] = f2h(a.w);
  o[4] = f2h(b.x); o[5] = f2h(b.y); o[6] = f2h(b.z); o[7] = f2h(b.w);
  *(bf16x8*)(d + i) = o;
}

// one block per row of 4096 f16 scores; fp32 softmax; in-place f16 probs
__global__ __launch_bounds__(256) void softmax_rows(short* __restrict__ S) {
  const size_t row = blockIdx.x;
  short* rp = S + row * 4096;
  const int tid = threadIdx.x;
  const int lane = tid & 63, wid = tid >> 6;
  float v[16];
#pragma unroll
  for (int c = 0; c < 2; c++) {
    bf16x8 xv = *(const bf16x8*)(rp + (c * 256 + tid) * 8);
#pragma unroll
    for (int j = 0; j < 8; j++) v[c * 8 + j] = h2f(xv[j]);
  }
  float m = v[0];
#pragma unroll
  for (int i = 1; i < 16; i++) m = fmaxf(m, v[i]);
#pragma unroll
  for (int off = 32; off >= 1; off >>= 1) m = fmaxf(m, __shfl_xor(m, off));
  __shared__ float red[8];
  if (lane == 0) red[wid] = m;
  __syncthreads();
  m = fmaxf(fmaxf(red[0], red[1]), fmaxf(red[2], red[3]));
  float s = 0.f;
#pragma unroll
  for (int i = 0; i < 16; i++) {
    v[i] = __expf(v[i] - m);
    s += v[i];
  }
#pragma unroll
  for (int off = 32; off >= 1; off >>= 1) s += __shfl_xor(s, off);
  if (lane == 0) red[4 + wid] = s;
  __syncthreads();
  s = (red[4] + red[5]) + (red[6] + red[7]);
  const float rs = 1.0f / s;
#pragma unroll
  for (int c = 0; c < 2; c++) {
    bf16x8 o;
#pragma unroll
    for (int j = 0; j < 8; j++) o[j] = f2h(v[c * 8 + j] * rs);
    *(bf16x8*)(rp + (c * 256 + tid) * 8) = o;
  }
}

extern "C" void kernel_launch(void* const* d_in, const int* in_sizes, int n_in,
                              void* d_out, int out_size, void* d_ws,
                              size_t ws_size, hipStream_t stream) {
  const float* x   = (const float*)d_in[0];
  const float* thw = (const float*)d_in[1];
  const float* thb = (const float*)d_in[2];
  const float* phw = (const float*)d_in[3];
  const float* phb = (const float*)d_in[4];
  const float* gw  = (const float*)d_in[5];
  const float* gbi = (const float*)d_in[6];
  const float* Ww  = (const float*)d_in[7];
  const float* Wb  = (const float*)d_in[8];
  float* out = (float*)d_out;

  // B=4, N=4096, D=2048, E=1024.  ws footprint 184,557,568 B (proven size)
  char* ws = (char*)d_ws;
  short* xf   = (short*)(ws);                // 67,108,864 B (16384x2048 f16)
  short* wcat = (short*)(ws + 67108864);     //  8,388,608 B (theta|phi 2048x2048)
  short* gwb  = (short*)(ws + 75497472);     //  4,194,304 B (1024x2048)
  short* wWb  = (short*)(ws + 79691776);     //  4,194,304 B (2048x1024)
  float* bc   = (float*)(ws + 83886080);     //  8,192 B (theta_b|phi_b)
  short* tpf  = (short*)(ws + 83894272);     // 67,108,864 B (theta|phi; later y)
  short* gT   = (short*)(ws + 151003136);    // 33,554,432 B (4x1024x4096)
  short* sc   = (short*)(ws);                // 67,108,864 B (2x4096x4096, over xf)

  // 1) fp32 -> f16 conversions
  cvt_f32_f16<<<16384, 256, 0, stream>>>(x, xf, 33554432);
  cvt_f32_f16<<<1024, 256, 0, stream>>>(thw, wcat, 2097152);
  cvt_f32_f16<<<1024, 256, 0, stream>>>(phw, wcat + 2097152, 2097152);
  cvt_f32_f16<<<1024, 256, 0, stream>>>(gw, gwb, 2097152);
  cvt_f32_f16<<<1024, 256, 0, stream>>>(Ww, wWb, 2097152);
  hipMemcpyAsync(bc, thb, 4096, hipMemcpyDeviceToDevice, stream);
  hipMemcpyAsync(bc + 1024, phb, 4096, hipMemcpyDeviceToDevice, stream);

  // 2) proj: [theta|phi] = x @ wcat^T + bias   (16384 x 2048, K=2048)
  gemm32<2048, 1, 1, 0><<<dim3(8, 64, 1), 256, 0, stream>>>(
      xf, 2048, 0L, wcat, 2048, 0L, tpf, 2048, 0L, bc, nullptr, 0L);

  // 3) gT[b] = g_w @ x_b^T + g_b[row]   (1024 x 4096 per batch, K=2048)
  gemm32<2048, 1, 2, 0><<<dim3(16, 4, 4), 256, 0, stream>>>(
      gwb, 2048, 0L, xf, 2048, 8388608L, gT, 4096, 4194304L, gbi, nullptr, 0L);

  // 4) per batch-PAIR p: scores(z=2) -> softmax -> y(z=2) -> z(z=2)
  //    sc pair overlays xf (dead after gT); y overwrites consumed theta/phi.
  for (int p = 0; p < 2; ++p) {
    const short* tp = tpf + (size_t)p * 16777216;
    gemm32<1024, 1, 0, 0><<<dim3(16, 16, 2), 256, 0, stream>>>(
        tp, 2048, 8388608L, tp + 1024, 2048, 8388608L,
        sc, 4096, 16777216L, nullptr, nullptr, 0L);
    softmax_rows<<<8192, 256, 0, stream>>>(sc);
    short* yp = tpf + (size_t)p * 16777216;  // pair-p theta/phi now dead
    gemm32<4096, 1, 0, 0><<<dim3(4, 16, 2), 256, 0, stream>>>(
        sc, 4096, 16777216L, gT + (size_t)p * 8388608, 4096, 4194304L,
        yp, 1024, 4194304L, nullptr, nullptr, 0L);
    gemm32<1024, 0, 1, 1><<<dim3(8, 16, 2), 256, 0, stream>>>(
        yp, 1024, 4194304L, wWb, 1024, 0L,
        out + (size_t)p * 16777216, 2048, 8388608L,
        Wb, x + (size_t)p * 16777216, 8388608L);
  }
}

// Round 13
// 754.055 us; speedup vs baseline: 1.0926x; 1.0926x over previous
//
#include <hip/hip_runtime.h>

typedef short bf16x8 __attribute__((ext_vector_type(8)));
typedef _Float16 f16x8 __attribute__((ext_vector_type(8)));
typedef float f32x4 __attribute__((ext_vector_type(4)));

__device__ __forceinline__ short f2h(float f) {
  _Float16 h = (_Float16)f;
  return __builtin_bit_cast(short, h);
}
__device__ __forceinline__ float h2f(short s) {
  return (float)__builtin_bit_cast(_Float16, s);
}

__device__ __forceinline__ void gload16(const void* g, void* lds) {
  __builtin_amdgcn_global_load_lds(
      (const __attribute__((address_space(1))) unsigned*)g,
      (__attribute__((address_space(3))) unsigned*)lds, 16, 0, 0);
}

// ---------------------------------------------------------------------------
// 256xBN f16 NT-GEMM, r6 base (8 waves 2Mx4N, BK=64, dbuf LDS, 0-conflict
// swizzle, counted vmcnt) + m201-style 4-phase K-tile interleave:
//  tile t: stage(t+1) -> vmcnt(GL) -> barrier   [tile t collectively resident]
//  phase p=0..3 (quadrant = m-frags {2p,2p+1}):
//    12 ds_read_b128 (A 4 + B 2NF) -> barrier -> lgkmcnt(0)
//    -> setprio(1) 16 MFMA setprio(0)
//  trailing barrier after phase 3 (protects buf[(t+1)&1] overwrite: all
//  waves' phase-3 reads lgkm-confirmed before any next-tile stage issues).
// Phase overlap: a wave finishing MFMA(p) issues ds(p+1) while its SIMD
// partner still MFMAs(p) -> LDS and MFMA pipes interleave across waves.
// Per-acc K-order identical to r6 -> absmax must stay exactly 0.03125.
// ---------------------------------------------------------------------------
template <int NF, int K, int OMODE, int BIAS_MODE, int RES>
__global__ __launch_bounds__(512, 2) void gemmq(
    const short* __restrict__ A, int lda, long sA,
    const short* __restrict__ B, int ldb, long sB,
    void* __restrict__ Cv, int ldc, long sC,
    const float* __restrict__ bias, const float* __restrict__ resid, long sR) {
  constexpr int BN = NF * 64;
  constexpr int BNB = BN * 128;  // B-tile bytes per buffer
  constexpr int NT = K / 64;
  __shared__ char lds[65536 + 2 * BNB];  // A: 2x32KB, B: 2xBNB

  A += (size_t)blockIdx.z * sA;
  B += (size_t)blockIdx.z * sB;
  char* Cb = (char*)Cv + (size_t)blockIdx.z * sC * (OMODE == 0 ? 4 : 2);
  const float* res = resid ? resid + (size_t)blockIdx.z * sR : nullptr;

  const int tid = threadIdx.x;
  const int wid = tid >> 6, lane = tid & 63;
  const int wr = wid >> 2, wc = wid & 3;  // wave grid 2 (M) x 4 (N)
  const int fr = lane & 15, fq = lane >> 4;
  const size_t bm = (size_t)blockIdx.y * 256;
  const size_t bn = (size_t)blockIdx.x * BN;

  // staging: per chunk 64 rows x 128 B; thread covers row srow, 16 B at scolS
  const int srow = wid * 8 + (lane >> 3);                   // 0..63
  const int scolS = ((lane & 7) * 16) ^ ((srow & 7) << 4);  // inv-swizzled src
  const char* Ag = (const char*)A;
  const char* Bg = (const char*)B;

  // ds_read byte offsets (ks=0); row&7 == fr&7 for all fragments
  const int swz = (fr & 7) << 4;
  int aoff[8], boff[NF];
#pragma unroll
  for (int m = 0; m < 8; m++)
    aoff[m] = (wr * 128 + m * 16 + fr) * 128 + ((fq * 16) ^ swz);
#pragma unroll
  for (int n = 0; n < NF; n++)
    boff[n] = (wc * NF * 16 + n * 16 + fr) * 128 + ((fq * 16) ^ swz);

  f32x4 acc[8][NF];
#pragma unroll
  for (int m = 0; m < 8; m++)
#pragma unroll
    for (int n = 0; n < NF; n++) acc[m][n] = (f32x4){0.f, 0.f, 0.f, 0.f};

  auto stage = [&](int t, int d) {
    const int ktb = t * 128;  // byte offset along K
#pragma unroll
    for (int c = 0; c < 4; ++c)
      gload16(Ag + ((size_t)(bm + c * 64 + srow) * lda) * 2 + ktb + scolS,
              &lds[d * 32768 + c * 8192 + wid * 1024]);
#pragma unroll
    for (int c = 0; c < NF; ++c)
      gload16(Bg + ((size_t)(bn + c * 64 + srow) * ldb) * 2 + ktb + scolS,
              &lds[65536 + d * BNB + c * 8192 + wid * 1024]);
  };

  stage(0, 0);
  for (int t = 0; t < NT; ++t) {
    // tile prologue: stage t+1, own-arrival wait, collective barrier
    if (t + 1 < NT) stage(t + 1, (t + 1) & 1);
    __builtin_amdgcn_sched_barrier(0);
    if (t + 1 < NT) {
      if constexpr (NF == 4)
        asm volatile("s_waitcnt vmcnt(8)");  // tile t done; t+1 in flight
      else
        asm volatile("s_waitcnt vmcnt(6)");
    } else {
      asm volatile("s_waitcnt vmcnt(0)");
    }
    __builtin_amdgcn_sched_barrier(0);
    __builtin_amdgcn_s_barrier();  // all waves confirmed own loads -> buf full
    __builtin_amdgcn_sched_barrier(0);

    const int dA = (t & 1) * 32768;
    const int dB = 65536 + (t & 1) * BNB;
#pragma unroll
    for (int p = 0; p < 4; ++p) {
      f16x8 ar[2][2], br[2][NF];
#pragma unroll
      for (int ks = 0; ks < 2; ++ks) {
#pragma unroll
        for (int mm = 0; mm < 2; ++mm)
          ar[ks][mm] =
              *(const f16x8*)&lds[dA + (aoff[2 * p + mm] ^ (ks << 6))];
#pragma unroll
        for (int n = 0; n < NF; ++n)
          br[ks][n] = *(const f16x8*)&lds[dB + (boff[n] ^ (ks << 6))];
      }
      __builtin_amdgcn_sched_barrier(0);
      __builtin_amdgcn_s_barrier();  // phase lockstep: ds(p) ∥ MFMA(p-1) peers
      __builtin_amdgcn_sched_barrier(0);
      asm volatile("s_waitcnt lgkmcnt(0)");
      __builtin_amdgcn_sched_barrier(0);
      __builtin_amdgcn_s_setprio(1);
#pragma unroll
      for (int ks = 0; ks < 2; ++ks)
#pragma unroll
        for (int mm = 0; mm < 2; ++mm)
#pragma unroll
          for (int n = 0; n < NF; ++n)
            acc[2 * p + mm][n] = __builtin_amdgcn_mfma_f32_16x16x32_f16(
                ar[ks][mm], br[ks][n], acc[2 * p + mm][n], 0, 0, 0);
      __builtin_amdgcn_s_setprio(0);
      __builtin_amdgcn_sched_barrier(0);
    }
    __builtin_amdgcn_s_barrier();  // phase-3 reads confirmed before next stage
    __builtin_amdgcn_sched_barrier(0);
  }

#pragma unroll
  for (int m = 0; m < 8; m++) {
    const size_t row0 = bm + wr * 128 + m * 16 + fq * 4;
#pragma unroll
    for (int n = 0; n < NF; n++) {
      const size_t col = bn + wc * NF * 16 + n * 16 + fr;
      float bcol = (BIAS_MODE == 1) ? bias[col] : 0.f;
#pragma unroll
      for (int r = 0; r < 4; r++) {
        float val = acc[m][n][r];
        const size_t row = row0 + r;
        const size_t idx = row * (size_t)ldc + col;
        if (BIAS_MODE == 1) val += bcol;
        if (BIAS_MODE == 2) val += bias[row];
        if (RES) val += res[idx];
        if (OMODE == 0)
          ((float*)Cb)[idx] = val;
        else
          ((short*)Cb)[idx] = f2h(val);
      }
    }
  }
}

__global__ __launch_bounds__(256) void cvt_f32_f16(const float* __restrict__ s,
                                                   short* __restrict__ d, int n) {
  int i = (blockIdx.x * 256 + threadIdx.x) * 8;
  if (i >= n) return;
  const float4 a = *(const float4*)(s + i);
  const float4 b = *(const float4*)(s + i + 4);
  bf16x8 o;
  o[0] = f2h(a.x); o[1] = f2h(a.y); o[2] = f2h(a.z); o[3] = f2h(a.w);
  o[4] = f2h(b.x); o[5] = f2h(b.y); o[6] = f2h(b.z); o[7] = f2h(b.w);
  *(bf16x8*)(d + i) = o;
}

// one block per row of 4096 f16 scores; fp32 softmax; in-place f16 probs
__global__ __launch_bounds__(256) void softmax_rows(short* __restrict__ S) {
  const size_t row = blockIdx.x;
  short* rp = S + row * 4096;
  const int tid = threadIdx.x;
  const int lane = tid & 63, wid = tid >> 6;
  float v[16];
#pragma unroll
  for (int c = 0; c < 2; c++) {
    bf16x8 xv = *(const bf16x8*)(rp + (c * 256 + tid) * 8);
#pragma unroll
    for (int j = 0; j < 8; j++) v[c * 8 + j] = h2f(xv[j]);
  }
  float m = v[0];
#pragma unroll
  for (int i = 1; i < 16; i++) m = fmaxf(m, v[i]);
#pragma unroll
  for (int off = 32; off >= 1; off >>= 1) m = fmaxf(m, __shfl_xor(m, off));
  __shared__ float red[8];
  if (lane == 0) red[wid] = m;
  __syncthreads();
  m = fmaxf(fmaxf(red[0], red[1]), fmaxf(red[2], red[3]));
  float s = 0.f;
#pragma unroll
  for (int i = 0; i < 16; i++) {
    v[i] = __expf(v[i] - m);
    s += v[i];
  }
#pragma unroll
  for (int off = 32; off >= 1; off >>= 1) s += __shfl_xor(s, off);
  if (lane == 0) red[4 + wid] = s;
  __syncthreads();
  s = (red[4] + red[5]) + (red[6] + red[7]);
  const float rs = 1.0f / s;
#pragma unroll
  for (int c = 0; c < 2; c++) {
    bf16x8 o;
#pragma unroll
    for (int j = 0; j < 8; j++) o[j] = f2h(v[c * 8 + j] * rs);
    *(bf16x8*)(rp + (c * 256 + tid) * 8) = o;
  }
}

extern "C" void kernel_launch(void* const* d_in, const int* in_sizes, int n_in,
                              void* d_out, int out_size, void* d_ws,
                              size_t ws_size, hipStream_t stream) {
  const float* x   = (const float*)d_in[0];
  const float* thw = (const float*)d_in[1];
  const float* thb = (const float*)d_in[2];
  const float* phw = (const float*)d_in[3];
  const float* phb = (const float*)d_in[4];
  const float* gw  = (const float*)d_in[5];
  const float* gbi = (const float*)d_in[6];
  const float* Ww  = (const float*)d_in[7];
  const float* Wb  = (const float*)d_in[8];
  float* out = (float*)d_out;

  // B=4, N=4096, D=2048, E=1024.  ws footprint 184,557,568 B (proven size)
  char* ws = (char*)d_ws;
  short* xf   = (short*)(ws);                // 67,108,864 B (16384x2048 f16)
  short* wcat = (short*)(ws + 67108864);     //  8,388,608 B (theta|phi 2048x2048)
  short* gwb  = (short*)(ws + 75497472);     //  4,194,304 B (1024x2048)
  short* wWb  = (short*)(ws + 79691776);     //  4,194,304 B (2048x1024)
  float* bc   = (float*)(ws + 83886080);     //  8,192 B (theta_b|phi_b)
  short* tpf  = (short*)(ws + 83894272);     // 67,108,864 B (theta|phi; later y)
  short* gT   = (short*)(ws + 151003136);    // 33,554,432 B (4x1024x4096)
  short* sc   = (short*)(ws);                // 67,108,864 B (2x4096x4096, over xf)

  // 1) fp32 -> f16 conversions
  cvt_f32_f16<<<16384, 256, 0, stream>>>(x, xf, 33554432);
  cvt_f32_f16<<<1024, 256, 0, stream>>>(thw, wcat, 2097152);
  cvt_f32_f16<<<1024, 256, 0, stream>>>(phw, wcat + 2097152, 2097152);
  cvt_f32_f16<<<1024, 256, 0, stream>>>(gw, gwb, 2097152);
  cvt_f32_f16<<<1024, 256, 0, stream>>>(Ww, wWb, 2097152);
  hipMemcpyAsync(bc, thb, 4096, hipMemcpyDeviceToDevice, stream);
  hipMemcpyAsync(bc + 1024, phb, 4096, hipMemcpyDeviceToDevice, stream);

  // 2) proj: [theta|phi] = x @ wcat^T + bias   (16384 x 2048, K=2048)
  gemmq<4, 2048, 1, 1, 0><<<dim3(8, 64, 1), 512, 0, stream>>>(
      xf, 2048, 0L, wcat, 2048, 0L, tpf, 2048, 0L, bc, nullptr, 0L);

  // 3) gT[b] = g_w @ x_b^T + g_b[row]   (1024 x 4096 per batch, K=2048)
  gemmq<4, 2048, 1, 2, 0><<<dim3(16, 4, 4), 512, 0, stream>>>(
      gwb, 2048, 0L, xf, 2048, 8388608L, gT, 4096, 4194304L, gbi, nullptr, 0L);

  // 4) per batch-PAIR p: scores(z=2) -> softmax -> y(z=2) -> z(z=2)
  //    sc pair overlays xf (dead after gT); y overwrites consumed theta/phi.
  for (int p = 0; p < 2; ++p) {
    const short* tp = tpf + (size_t)p * 16777216;
    gemmq<4, 1024, 1, 0, 0><<<dim3(16, 16, 2), 512, 0, stream>>>(
        tp, 2048, 8388608L, tp + 1024, 2048, 8388608L,
        sc, 4096, 16777216L, nullptr, nullptr, 0L);
    softmax_rows<<<8192, 256, 0, stream>>>(sc);
    short* yp = tpf + (size_t)p * 16777216;  // pair-p theta/phi now dead
    gemmq<2, 4096, 1, 0, 0><<<dim3(8, 16, 2), 512, 0, stream>>>(
        sc, 4096, 16777216L, gT + (size_t)p * 8388608, 4096, 4194304L,
        yp, 1024, 4194304L, nullptr, nullptr, 0L);
    gemmq<4, 1024, 0, 1, 1><<<dim3(8, 16, 2), 512, 0, stream>>>(
        yp, 1024, 4194304L, wWb, 1024, 0L,
        out + (size_t)p * 16777216, 2048, 8388608L,
        Wb, x + (size_t)p * 16777216, 8388608L);
  }
}

// Round 14
// 703.505 us; speedup vs baseline: 1.1711x; 1.0719x over previous
//
#include <hip/hip_runtime.h>

typedef short bf16x8 __attribute__((ext_vector_type(8)));
typedef _Float16 f16x8 __attribute__((ext_vector_type(8)));
typedef float f32x4 __attribute__((ext_vector_type(4)));

__device__ __forceinline__ short f2h(float f) {
  _Float16 h = (_Float16)f;
  return __builtin_bit_cast(short, h);
}
__device__ __forceinline__ float h2f(short s) {
  return (float)__builtin_bit_cast(_Float16, s);
}

__device__ __forceinline__ void gload16(const void* g, void* lds) {
  __builtin_amdgcn_global_load_lds(
      (const __attribute__((address_space(1))) unsigned*)g,
      (__attribute__((address_space(3))) unsigned*)lds, 16, 0, 0);
}

// ---------------------------------------------------------------------------
// r6 structure (best measured: 967 TF proj, 0 bank conflicts): 256xBN tile,
// BK=64, 512 thr = 8 waves (2Mx4N), LDS double-buffered, raw s_barrier +
// counted vmcnt (next tile's loads stay in flight across both barriers),
// 16B-granule XOR swizzle (col ^= (row&7)<<4) applied on the global source
// (linear gload_lds dest) and on ds_read (rule #21 both-sides).
// Four schedule restructures (r7/r8/r11-12/r13) all failed to beat this;
// kept frozen.
// ---------------------------------------------------------------------------
template <int NF, int K, int OMODE, int BIAS_MODE, int RES>
__global__ __launch_bounds__(512, 2) void gemm256(
    const short* __restrict__ A, int lda, long sA,
    const short* __restrict__ B, int ldb, long sB,
    void* __restrict__ Cv, int ldc, long sC,
    const float* __restrict__ bias, const float* __restrict__ resid, long sR) {
  constexpr int BN = NF * 64;
  constexpr int BNB = BN * 128;  // B-tile bytes per buffer
  constexpr int NT = K / 64;
  __shared__ char lds[65536 + 2 * BNB];  // A: 2x32KB, B: 2xBNB

  A += (size_t)blockIdx.z * sA;
  B += (size_t)blockIdx.z * sB;
  char* Cb = (char*)Cv + (size_t)blockIdx.z * sC * (OMODE == 0 ? 4 : 2);
  const float* res = resid ? resid + (size_t)blockIdx.z * sR : nullptr;

  const int tid = threadIdx.x;
  const int wid = tid >> 6, lane = tid & 63;
  const int wr = wid >> 2, wc = wid & 3;  // wave grid 2 (M) x 4 (N)
  const int fr = lane & 15, fq = lane >> 4;
  const size_t bm = (size_t)blockIdx.y * 256;
  const size_t bn = (size_t)blockIdx.x * BN;

  // staging: per chunk 64 rows x 128 B; thread covers row srow, 16 B at scolS
  const int srow = wid * 8 + (lane >> 3);                   // 0..63
  const int scolS = ((lane & 7) * 16) ^ ((srow & 7) << 4);  // inv-swizzled src
  const char* Ag = (const char*)A;
  const char* Bg = (const char*)B;

  // ds_read byte offsets (ks=0, buffer 0); row&7 == fr&7 for all fragments
  const int swz = (fr & 7) << 4;
  int aoff[8], boff[NF];
#pragma unroll
  for (int m = 0; m < 8; m++)
    aoff[m] = (wr * 128 + m * 16 + fr) * 128 + ((fq * 16) ^ swz);
#pragma unroll
  for (int n = 0; n < NF; n++)
    boff[n] = (wc * NF * 16 + n * 16 + fr) * 128 + ((fq * 16) ^ swz);

  f32x4 acc[8][NF];
#pragma unroll
  for (int m = 0; m < 8; m++)
#pragma unroll
    for (int n = 0; n < NF; n++) acc[m][n] = (f32x4){0.f, 0.f, 0.f, 0.f};

  auto stage = [&](int t, int d) {
    const int ktb = t * 128;  // byte offset along K
#pragma unroll
    for (int c = 0; c < 4; ++c)
      gload16(Ag + ((size_t)(bm + c * 64 + srow) * lda) * 2 + ktb + scolS,
              &lds[d * 32768 + c * 8192 + wid * 1024]);
#pragma unroll
    for (int c = 0; c < NF; ++c)
      gload16(Bg + ((size_t)(bn + c * 64 + srow) * ldb) * 2 + ktb + scolS,
              &lds[65536 + d * BNB + c * 8192 + wid * 1024]);
  };

  stage(0, 0);
  int cur = 0;
#pragma unroll 2
  for (int t = 0; t < NT; ++t) {
    if (t + 1 < NT) stage(t + 1, cur ^ 1);
    __builtin_amdgcn_sched_barrier(0);
    if (t + 1 < NT) {
      if constexpr (NF == 4)
        asm volatile("s_waitcnt vmcnt(8)");  // tile t done; t+1's 8 in flight
      else
        asm volatile("s_waitcnt vmcnt(6)");
    } else {
      asm volatile("s_waitcnt vmcnt(0)");
    }
    __builtin_amdgcn_sched_barrier(0);
    __builtin_amdgcn_s_barrier();  // all waves see buf[cur] full
    __builtin_amdgcn_sched_barrier(0);
    {
      const int dA = cur * 32768, dB = 65536 + cur * BNB;
#pragma unroll
      for (int ks = 0; ks < 2; ++ks) {
        f16x8 ar[8], br[NF];
#pragma unroll
        for (int m = 0; m < 8; m++)
          ar[m] = *(const f16x8*)&lds[dA + (aoff[m] ^ (ks << 6))];
#pragma unroll
        for (int n = 0; n < NF; n++)
          br[n] = *(const f16x8*)&lds[dB + (boff[n] ^ (ks << 6))];
#pragma unroll
        for (int m = 0; m < 8; m++)
#pragma unroll
          for (int n = 0; n < NF; n++)
            acc[m][n] = __builtin_amdgcn_mfma_f32_16x16x32_f16(
                ar[m], br[n], acc[m][n], 0, 0, 0);
      }
    }
    __builtin_amdgcn_sched_barrier(0);
    __builtin_amdgcn_s_barrier();  // buf[cur] free for overwrite next iter
    __builtin_amdgcn_sched_barrier(0);
    cur ^= 1;
  }

#pragma unroll
  for (int m = 0; m < 8; m++) {
    const size_t row0 = bm + wr * 128 + m * 16 + fq * 4;
#pragma unroll
    for (int n = 0; n < NF; n++) {
      const size_t col = bn + wc * NF * 16 + n * 16 + fr;
      float bcol = (BIAS_MODE == 1) ? bias[col] : 0.f;
#pragma unroll
      for (int r = 0; r < 4; r++) {
        float val = acc[m][n][r];
        const size_t row = row0 + r;
        const size_t idx = row * (size_t)ldc + col;
        if (BIAS_MODE == 1) val += bcol;
        if (BIAS_MODE == 2) val += bias[row];
        if (RES) val += res[idx];
        if (OMODE == 0)
          ((float*)Cb)[idx] = val;
        else
          ((short*)Cb)[idx] = f2h(val);
      }
    }
  }
}

__global__ __launch_bounds__(256) void cvt_f32_f16(const float* __restrict__ s,
                                                   short* __restrict__ d, int n) {
  int i = (blockIdx.x * 256 + threadIdx.x) * 8;
  if (i >= n) return;
  const float4 a = *(const float4*)(s + i);
  const float4 b = *(const float4*)(s + i + 4);
  bf16x8 o;
  o[0] = f2h(a.x); o[1] = f2h(a.y); o[2] = f2h(a.z); o[3] = f2h(a.w);
  o[4] = f2h(b.x); o[5] = f2h(b.y); o[6] = f2h(b.z); o[7] = f2h(b.w);
  *(bf16x8*)(d + i) = o;
}

// merged weight conversion: 4 x (2M f32 -> f16) + theta_b|phi_b bias concat.
// 6 dispatches -> 1 (launch-overhead cut; graph-capture friendly).
__global__ __launch_bounds__(256) void cvt_weights(
    const float* __restrict__ thw, const float* __restrict__ phw,
    const float* __restrict__ gw, const float* __restrict__ Ww,
    short* __restrict__ wcat, short* __restrict__ gwb, short* __restrict__ wWb,
    const float* __restrict__ thb, const float* __restrict__ phb,
    float* __restrict__ bc) {
  const int b = blockIdx.x;  // 0..4095
  const int seg = b >> 10, ib = b & 1023;
  const float* s;
  short* d;
  if (seg == 0) { s = thw; d = wcat; }
  else if (seg == 1) { s = phw; d = wcat + 2097152; }
  else if (seg == 2) { s = gw; d = gwb; }
  else { s = Ww; d = wWb; }
  const int i = (ib * 256 + threadIdx.x) * 8;
  const float4 a = *(const float4*)(s + i);
  const float4 v = *(const float4*)(s + i + 4);
  bf16x8 o;
  o[0] = f2h(a.x); o[1] = f2h(a.y); o[2] = f2h(a.z); o[3] = f2h(a.w);
  o[4] = f2h(v.x); o[5] = f2h(v.y); o[6] = f2h(v.z); o[7] = f2h(v.w);
  *(bf16x8*)(d + i) = o;
  if (b == 0) {  // bias concat: 256 thr x 8 f32 = 2048
    const int j = threadIdx.x * 8;
#pragma unroll
    for (int k = 0; k < 8; ++k) {
      const int jj = j + k;
      bc[jj] = (jj < 1024) ? thb[jj] : phb[jj - 1024];
    }
  }
}

// one block per row of 4096 f16 scores; fp32 softmax; in-place f16 probs
__global__ __launch_bounds__(256) void softmax_rows(short* __restrict__ S) {
  const size_t row = blockIdx.x;
  short* rp = S + row * 4096;
  const int tid = threadIdx.x;
  const int lane = tid & 63, wid = tid >> 6;
  float v[16];
#pragma unroll
  for (int c = 0; c < 2; c++) {
    bf16x8 xv = *(const bf16x8*)(rp + (c * 256 + tid) * 8);
#pragma unroll
    for (int j = 0; j < 8; j++) v[c * 8 + j] = h2f(xv[j]);
  }
  float m = v[0];
#pragma unroll
  for (int i = 1; i < 16; i++) m = fmaxf(m, v[i]);
#pragma unroll
  for (int off = 32; off >= 1; off >>= 1) m = fmaxf(m, __shfl_xor(m, off));
  __shared__ float red[8];
  if (lane == 0) red[wid] = m;
  __syncthreads();
  m = fmaxf(fmaxf(red[0], red[1]), fmaxf(red[2], red[3]));
  float s = 0.f;
#pragma unroll
  for (int i = 0; i < 16; i++) {
    v[i] = __expf(v[i] - m);
    s += v[i];
  }
#pragma unroll
  for (int off = 32; off >= 1; off >>= 1) s += __shfl_xor(s, off);
  if (lane == 0) red[4 + wid] = s;
  __syncthreads();
  s = (red[4] + red[5]) + (red[6] + red[7]);
  const float rs = 1.0f / s;
#pragma unroll
  for (int c = 0; c < 2; c++) {
    bf16x8 o;
#pragma unroll
    for (int j = 0; j < 8; j++) o[j] = f2h(v[c * 8 + j] * rs);
    *(bf16x8*)(rp + (c * 256 + tid) * 8) = o;
  }
}

extern "C" void kernel_launch(void* const* d_in, const int* in_sizes, int n_in,
                              void* d_out, int out_size, void* d_ws,
                              size_t ws_size, hipStream_t stream) {
  const float* x   = (const float*)d_in[0];
  const float* thw = (const float*)d_in[1];
  const float* thb = (const float*)d_in[2];
  const float* phw = (const float*)d_in[3];
  const float* phb = (const float*)d_in[4];
  const float* gw  = (const float*)d_in[5];
  const float* gbi = (const float*)d_in[6];
  const float* Ww  = (const float*)d_in[7];
  const float* Wb  = (const float*)d_in[8];
  float* out = (float*)d_out;

  // B=4, N=4096, D=2048, E=1024.  ws footprint 184,557,568 B (proven size)
  char* ws = (char*)d_ws;
  short* xf   = (short*)(ws);                // 67,108,864 B (16384x2048 f16)
  short* wcat = (short*)(ws + 67108864);     //  8,388,608 B (theta|phi 2048x2048)
  short* gwb  = (short*)(ws + 75497472);     //  4,194,304 B (1024x2048)
  short* wWb  = (short*)(ws + 79691776);     //  4,194,304 B (2048x1024)
  float* bc   = (float*)(ws + 83886080);     //  8,192 B (theta_b|phi_b)
  short* tpf  = (short*)(ws + 83894272);     // 67,108,864 B (theta|phi; later y)
  short* gT   = (short*)(ws + 151003136);    // 33,554,432 B (4x1024x4096)
  short* sc   = (short*)(ws);                // 67,108,864 B (2x4096x4096, over xf)

  // 1) fp32 -> f16 conversions (x big pass + single merged weight pass)
  cvt_f32_f16<<<16384, 256, 0, stream>>>(x, xf, 33554432);
  cvt_weights<<<4096, 256, 0, stream>>>(thw, phw, gw, Ww, wcat, gwb, wWb, thb,
                                        phb, bc);

  // 2) proj: [theta|phi] = x @ wcat^T + bias   (16384 x 2048, K=2048)
  gemm256<4, 2048, 1, 1, 0><<<dim3(8, 64, 1), 512, 0, stream>>>(
      xf, 2048, 0L, wcat, 2048, 0L, tpf, 2048, 0L, bc, nullptr, 0L);

  // 3) gT[b] = g_w @ x_b^T + g_b[row]   (1024 x 4096 per batch, K=2048)
  gemm256<4, 2048, 1, 2, 0><<<dim3(16, 4, 4), 512, 0, stream>>>(
      gwb, 2048, 0L, xf, 2048, 8388608L, gT, 4096, 4194304L, gbi, nullptr, 0L);

  // 4) per batch-PAIR p: scores(z=2) -> softmax -> y(z=2) -> z(z=2)
  //    sc pair overlays xf (dead after gT); y overwrites consumed theta/phi.
  for (int p = 0; p < 2; ++p) {
    const short* tp = tpf + (size_t)p * 16777216;
    gemm256<4, 1024, 1, 0, 0><<<dim3(16, 16, 2), 512, 0, stream>>>(
        tp, 2048, 8388608L, tp + 1024, 2048, 8388608L,
        sc, 4096, 16777216L, nullptr, nullptr, 0L);
    softmax_rows<<<8192, 256, 0, stream>>>(sc);
    short* yp = tpf + (size_t)p * 16777216;  // pair-p theta/phi now dead
    gemm256<2, 4096, 1, 0, 0><<<dim3(8, 16, 2), 512, 0, stream>>>(
        sc, 4096, 16777216L, gT + (size_t)p * 8388608, 4096, 4194304L,
        yp, 1024, 4194304L, nullptr, nullptr, 0L);
    gemm256<4, 1024, 0, 1, 1><<<dim3(8, 16, 2), 512, 0, stream>>>(
        yp, 1024, 4194304L, wWb, 1024, 0L,
        out + (size_t)p * 16777216, 2048, 8388608L,
        Wb, x + (size_t)p * 16777216, 8388608L);
  }
}

// Round 16
// 700.632 us; speedup vs baseline: 1.1759x; 1.0041x over previous
//
#include <hip/hip_runtime.h>

typedef short bf16x8 __attribute__((ext_vector_type(8)));
typedef _Float16 f16x8 __attribute__((ext_vector_type(8)));
typedef float f32x4 __attribute__((ext_vector_type(4)));

__device__ __forceinline__ short f2h(float f) {
  _Float16 h = (_Float16)f;
  return __builtin_bit_cast(short, h);
}
__device__ __forceinline__ float h2f(short s) {
  return (float)__builtin_bit_cast(_Float16, s);
}

__device__ __forceinline__ void gload16(const void* g, void* lds) {
  __builtin_amdgcn_global_load_lds(
      (const __attribute__((address_space(1))) unsigned*)g,
      (__attribute__((address_space(3))) unsigned*)lds, 16, 0, 0);
}

// ---------------------------------------------------------------------------
// r6 base (256xBN, BK=64, 8 waves 2Mx4N, dbuf LDS, 0-conflict swizzle,
// counted vmcnt) + in-tile 5-phase quadrant interleave at EQUAL LDS traffic
// (24 b128/wave/tile, same as r6; r13's failure was 32):
//  P0: read Aq0(m0,m1 ks01)+B.ks0 -> bar -> lgkm0 -> MFMA {m0,m1}xks0
//  P1: read B.ks1+Aq1            -> bar -> lgkm0 -> MFMA {m0,m1}xks1
//  P2: read Aq2                  -> bar -> lgkm0 -> MFMA {m2,m3}xks01
//  P3: read Aq3                  -> bar -> lgkm0 -> MFMA {m4,m5}xks01
//  P4: (no reads)                                -> MFMA {m6,m7}xks01
// A-quads roll through two register sets (aA/aB); B ks0/ks1 live whole tile.
// Per-acc ks order (ks0 then ks1) identical to r6 -> absmax bit-stable.
// Tail barrier after P4 = buffer-overwrite safety (own reads lgkm-confirmed
// in P3 before it).
// ---------------------------------------------------------------------------
template <int NF, int K, int OMODE, int BIAS_MODE, int RES>
__global__ __launch_bounds__(512, 2) void gemmph(
    const short* __restrict__ A, int lda, long sA,
    const short* __restrict__ B, int ldb, long sB,
    void* __restrict__ Cv, int ldc, long sC,
    const float* __restrict__ bias, const float* __restrict__ resid, long sR) {
  constexpr int BN = NF * 64;
  constexpr int BNB = BN * 128;  // B-tile bytes per buffer
  constexpr int NT = K / 64;
  __shared__ char lds[65536 + 2 * BNB];  // A: 2x32KB, B: 2xBNB

  A += (size_t)blockIdx.z * sA;
  B += (size_t)blockIdx.z * sB;
  char* Cb = (char*)Cv + (size_t)blockIdx.z * sC * (OMODE == 0 ? 4 : 2);
  const float* res = resid ? resid + (size_t)blockIdx.z * sR : nullptr;

  const int tid = threadIdx.x;
  const int wid = tid >> 6, lane = tid & 63;
  const int wr = wid >> 2, wc = wid & 3;  // wave grid 2 (M) x 4 (N)
  const int fr = lane & 15, fq = lane >> 4;
  const size_t bm = (size_t)blockIdx.y * 256;
  const size_t bn = (size_t)blockIdx.x * BN;

  // staging: per chunk 64 rows x 128 B; thread covers row srow, 16 B at scolS
  const int srow = wid * 8 + (lane >> 3);                   // 0..63
  const int scolS = ((lane & 7) * 16) ^ ((srow & 7) << 4);  // inv-swizzled src
  const char* Ag = (const char*)A;
  const char* Bg = (const char*)B;

  // ds_read byte offsets (ks=0); ks1 = ^64. row&7 == fr&7 for all fragments
  const int swz = (fr & 7) << 4;
  int aoff[8], boff[NF];
#pragma unroll
  for (int m = 0; m < 8; m++)
    aoff[m] = (wr * 128 + m * 16 + fr) * 128 + ((fq * 16) ^ swz);
#pragma unroll
  for (int n = 0; n < NF; n++)
    boff[n] = (wc * NF * 16 + n * 16 + fr) * 128 + ((fq * 16) ^ swz);

  f32x4 acc[8][NF];
#pragma unroll
  for (int m = 0; m < 8; m++)
#pragma unroll
    for (int n = 0; n < NF; n++) acc[m][n] = (f32x4){0.f, 0.f, 0.f, 0.f};

  auto stage = [&](int t, int d) {
    const int ktb = t * 128;  // byte offset along K
#pragma unroll
    for (int c = 0; c < 4; ++c)
      gload16(Ag + ((size_t)(bm + c * 64 + srow) * lda) * 2 + ktb + scolS,
              &lds[d * 32768 + c * 8192 + wid * 1024]);
#pragma unroll
    for (int c = 0; c < NF; ++c)
      gload16(Bg + ((size_t)(bn + c * 64 + srow) * ldb) * 2 + ktb + scolS,
              &lds[65536 + d * BNB + c * 8192 + wid * 1024]);
  };

#define SBAR                             \
  __builtin_amdgcn_sched_barrier(0);     \
  __builtin_amdgcn_s_barrier();          \
  __builtin_amdgcn_sched_barrier(0);     \
  asm volatile("s_waitcnt lgkmcnt(0)");  \
  __builtin_amdgcn_sched_barrier(0)

  stage(0, 0);
  for (int t = 0; t < NT; ++t) {
    if (t + 1 < NT) stage(t + 1, (t + 1) & 1);
    __builtin_amdgcn_sched_barrier(0);
    if (t + 1 < NT) {
      if constexpr (NF == 4)
        asm volatile("s_waitcnt vmcnt(8)");  // tile t done; t+1's 8 in flight
      else
        asm volatile("s_waitcnt vmcnt(6)");
    } else {
      asm volatile("s_waitcnt vmcnt(0)");
    }
    __builtin_amdgcn_sched_barrier(0);
    __builtin_amdgcn_s_barrier();  // buf[t&1] resident block-wide
    __builtin_amdgcn_sched_barrier(0);

    const int dA = (t & 1) * 32768, dB = 65536 + (t & 1) * BNB;
    f16x8 aA[4], aB[4], b0[NF], b1[NF];

    // P0: A-quad0 (m0,m1 x ks01) + B ks0
    aA[0] = *(const f16x8*)&lds[dA + aoff[0]];
    aA[1] = *(const f16x8*)&lds[dA + (aoff[0] ^ 64)];
    aA[2] = *(const f16x8*)&lds[dA + aoff[1]];
    aA[3] = *(const f16x8*)&lds[dA + (aoff[1] ^ 64)];
#pragma unroll
    for (int n = 0; n < NF; n++) b0[n] = *(const f16x8*)&lds[dB + boff[n]];
    SBAR;
    __builtin_amdgcn_s_setprio(1);
#pragma unroll
    for (int n = 0; n < NF; n++) {
      acc[0][n] = __builtin_amdgcn_mfma_f32_16x16x32_f16(aA[0], b0[n],
                                                         acc[0][n], 0, 0, 0);
      acc[1][n] = __builtin_amdgcn_mfma_f32_16x16x32_f16(aA[2], b0[n],
                                                         acc[1][n], 0, 0, 0);
    }
    __builtin_amdgcn_s_setprio(0);

    // P1: B ks1 + A-quad1 (m2,m3)
#pragma unroll
    for (int n = 0; n < NF; n++)
      b1[n] = *(const f16x8*)&lds[dB + (boff[n] ^ 64)];
    aB[0] = *(const f16x8*)&lds[dA + aoff[2]];
    aB[1] = *(const f16x8*)&lds[dA + (aoff[2] ^ 64)];
    aB[2] = *(const f16x8*)&lds[dA + aoff[3]];
    aB[3] = *(const f16x8*)&lds[dA + (aoff[3] ^ 64)];
    SBAR;
    __builtin_amdgcn_s_setprio(1);
#pragma unroll
    for (int n = 0; n < NF; n++) {
      acc[0][n] = __builtin_amdgcn_mfma_f32_16x16x32_f16(aA[1], b1[n],
                                                         acc[0][n], 0, 0, 0);
      acc[1][n] = __builtin_amdgcn_mfma_f32_16x16x32_f16(aA[3], b1[n],
                                                         acc[1][n], 0, 0, 0);
    }
    __builtin_amdgcn_s_setprio(0);

    // P2: A-quad2 (m4,m5); MFMA m2,m3 (ks0 then ks1 per acc)
    aA[0] = *(const f16x8*)&lds[dA + aoff[4]];
    aA[1] = *(const f16x8*)&lds[dA + (aoff[4] ^ 64)];
    aA[2] = *(const f16x8*)&lds[dA + aoff[5]];
    aA[3] = *(const f16x8*)&lds[dA + (aoff[5] ^ 64)];
    SBAR;
    __builtin_amdgcn_s_setprio(1);
#pragma unroll
    for (int n = 0; n < NF; n++) {
      acc[2][n] = __builtin_amdgcn_mfma_f32_16x16x32_f16(aB[0], b0[n],
                                                         acc[2][n], 0, 0, 0);
      acc[2][n] = __builtin_amdgcn_mfma_f32_16x16x32_f16(aB[1], b1[n],
                                                         acc[2][n], 0, 0, 0);
      acc[3][n] = __builtin_amdgcn_mfma_f32_16x16x32_f16(aB[2], b0[n],
                                                         acc[3][n], 0, 0, 0);
      acc[3][n] = __builtin_amdgcn_mfma_f32_16x16x32_f16(aB[3], b1[n],
                                                         acc[3][n], 0, 0, 0);
    }
    __builtin_amdgcn_s_setprio(0);

    // P3: A-quad3 (m6,m7); MFMA m4,m5
    aB[0] = *(const f16x8*)&lds[dA + aoff[6]];
    aB[1] = *(const f16x8*)&lds[dA + (aoff[6] ^ 64)];
    aB[2] = *(const f16x8*)&lds[dA + aoff[7]];
    aB[3] = *(const f16x8*)&lds[dA + (aoff[7] ^ 64)];
    SBAR;
    __builtin_amdgcn_s_setprio(1);
#pragma unroll
    for (int n = 0; n < NF; n++) {
      acc[4][n] = __builtin_amdgcn_mfma_f32_16x16x32_f16(aA[0], b0[n],
                                                         acc[4][n], 0, 0, 0);
      acc[4][n] = __builtin_amdgcn_mfma_f32_16x16x32_f16(aA[1], b1[n],
                                                         acc[4][n], 0, 0, 0);
      acc[5][n] = __builtin_amdgcn_mfma_f32_16x16x32_f16(aA[2], b0[n],
                                                         acc[5][n], 0, 0, 0);
      acc[5][n] = __builtin_amdgcn_mfma_f32_16x16x32_f16(aA[3], b1[n],
                                                         acc[5][n], 0, 0, 0);
    }
    __builtin_amdgcn_s_setprio(0);

    // P4: MFMA m6,m7 (no reads)
    __builtin_amdgcn_s_setprio(1);
#pragma unroll
    for (int n = 0; n < NF; n++) {
      acc[6][n] = __builtin_amdgcn_mfma_f32_16x16x32_f16(aB[0], b0[n],
                                                         acc[6][n], 0, 0, 0);
      acc[6][n] = __builtin_amdgcn_mfma_f32_16x16x32_f16(aB[1], b1[n],
                                                         acc[6][n], 0, 0, 0);
      acc[7][n] = __builtin_amdgcn_mfma_f32_16x16x32_f16(aB[2], b0[n],
                                                         acc[7][n], 0, 0, 0);
      acc[7][n] = __builtin_amdgcn_mfma_f32_16x16x32_f16(aB[3], b1[n],
                                                         acc[7][n], 0, 0, 0);
    }
    __builtin_amdgcn_s_setprio(0);
    __builtin_amdgcn_sched_barrier(0);
    __builtin_amdgcn_s_barrier();  // all reads of buf[t&1] done block-wide
    __builtin_amdgcn_sched_barrier(0);
  }
#undef SBAR

#pragma unroll
  for (int m = 0; m < 8; m++) {
    const size_t row0 = bm + wr * 128 + m * 16 + fq * 4;
#pragma unroll
    for (int n = 0; n < NF; n++) {
      const size_t col = bn + wc * NF * 16 + n * 16 + fr;
      float bcol = (BIAS_MODE == 1) ? bias[col] : 0.f;
#pragma unroll
      for (int r = 0; r < 4; r++) {
        float val = acc[m][n][r];
        const size_t row = row0 + r;
        const size_t idx = row * (size_t)ldc + col;
        if (BIAS_MODE == 1) val += bcol;
        if (BIAS_MODE == 2) val += bias[row];
        if (RES) val += res[idx];
        if (OMODE == 0)
          ((float*)Cb)[idx] = val;
        else
          ((short*)Cb)[idx] = f2h(val);
      }
    }
  }
}

__global__ __launch_bounds__(256) void cvt_f32_f16(const float* __restrict__ s,
                                                   short* __restrict__ d, int n) {
  int i = (blockIdx.x * 256 + threadIdx.x) * 8;
  if (i >= n) return;
  const float4 a = *(const float4*)(s + i);
  const float4 b = *(const float4*)(s + i + 4);
  bf16x8 o;
  o[0] = f2h(a.x); o[1] = f2h(a.y); o[2] = f2h(a.z); o[3] = f2h(a.w);
  o[4] = f2h(b.x); o[5] = f2h(b.y); o[6] = f2h(b.z); o[7] = f2h(b.w);
  *(bf16x8*)(d + i) = o;
}

// merged weight conversion: 4 x (2M f32 -> f16) + theta_b|phi_b bias concat.
__global__ __launch_bounds__(256) void cvt_weights(
    const float* __restrict__ thw, const float* __restrict__ phw,
    const float* __restrict__ gw, const float* __restrict__ Ww,
    short* __restrict__ wcat, short* __restrict__ gwb, short* __restrict__ wWb,
    const float* __restrict__ thb, const float* __restrict__ phb,
    float* __restrict__ bc) {
  const int b = blockIdx.x;  // 0..4095
  const int seg = b >> 10, ib = b & 1023;
  const float* s;
  short* d;
  if (seg == 0) { s = thw; d = wcat; }
  else if (seg == 1) { s = phw; d = wcat + 2097152; }
  else if (seg == 2) { s = gw; d = gwb; }
  else { s = Ww; d = wWb; }
  const int i = (ib * 256 + threadIdx.x) * 8;
  const float4 a = *(const float4*)(s + i);
  const float4 v = *(const float4*)(s + i + 4);
  bf16x8 o;
  o[0] = f2h(a.x); o[1] = f2h(a.y); o[2] = f2h(a.z); o[3] = f2h(a.w);
  o[4] = f2h(v.x); o[5] = f2h(v.y); o[6] = f2h(v.z); o[7] = f2h(v.w);
  *(bf16x8*)(d + i) = o;
  if (b == 0) {  // bias concat: 256 thr x 8 f32 = 2048
    const int j = threadIdx.x * 8;
#pragma unroll
    for (int k = 0; k < 8; ++k) {
      const int jj = j + k;
      bc[jj] = (jj < 1024) ? thb[jj] : phb[jj - 1024];
    }
  }
}

// one block per row of 4096 f16 scores; fp32 softmax; in-place f16 probs
__global__ __launch_bounds__(256) void softmax_rows(short* __restrict__ S) {
  const size_t row = blockIdx.x;
  short* rp = S + row * 4096;
  const int tid = threadIdx.x;
  const int lane = tid & 63, wid = tid >> 6;
  float v[16];
#pragma unroll
  for (int c = 0; c < 2; c++) {
    bf16x8 xv = *(const bf16x8*)(rp + (c * 256 + tid) * 8);
#pragma unroll
    for (int j = 0; j < 8; j++) v[c * 8 + j] = h2f(xv[j]);
  }
  float m = v[0];
#pragma unroll
  for (int i = 1; i < 16; i++) m = fmaxf(m, v[i]);
#pragma unroll
  for (int off = 32; off >= 1; off >>= 1) m = fmaxf(m, __shfl_xor(m, off));
  __shared__ float red[8];
  if (lane == 0) red[wid] = m;
  __syncthreads();
  m = fmaxf(fmaxf(red[0], red[1]), fmaxf(red[2], red[3]));
  float s = 0.f;
#pragma unroll
  for (int i = 0; i < 16; i++) {
    v[i] = __expf(v[i] - m);
    s += v[i];
  }
#pragma unroll
  for (int off = 32; off >= 1; off >>= 1) s += __shfl_xor(s, off);
  if (lane == 0) red[4 + wid] = s;
  __syncthreads();
  s = (red[4] + red[5]) + (red[6] + red[7]);
  const float rs = 1.0f / s;
#pragma unroll
  for (int c = 0; c < 2; c++) {
    bf16x8 o;
#pragma unroll
    for (int j = 0; j < 8; j++) o[j] = f2h(v[c * 8 + j] * rs);
    *(bf16x8*)(rp + (c * 256 + tid) * 8) = o;
  }
}

extern "C" void kernel_launch(void* const* d_in, const int* in_sizes, int n_in,
                              void* d_out, int out_size, void* d_ws,
                              size_t ws_size, hipStream_t stream) {
  const float* x   = (const float*)d_in[0];
  const float* thw = (const float*)d_in[1];
  const float* thb = (const float*)d_in[2];
  const float* phw = (const float*)d_in[3];
  const float* phb = (const float*)d_in[4];
  const float* gw  = (const float*)d_in[5];
  const float* gbi = (const float*)d_in[6];
  const float* Ww  = (const float*)d_in[7];
  const float* Wb  = (const float*)d_in[8];
  float* out = (float*)d_out;

  // B=4, N=4096, D=2048, E=1024.  ws footprint 184,557,568 B (proven size)
  char* ws = (char*)d_ws;
  short* xf   = (short*)(ws);                // 67,108,864 B (16384x2048 f16)
  short* wcat = (short*)(ws + 67108864);     //  8,388,608 B (theta|phi 2048x2048)
  short* gwb  = (short*)(ws + 75497472);     //  4,194,304 B (1024x2048)
  short* wWb  = (short*)(ws + 79691776);     //  4,194,304 B (2048x1024)
  float* bc   = (float*)(ws + 83886080);     //  8,192 B (theta_b|phi_b)
  short* tpf  = (short*)(ws + 83894272);     // 67,108,864 B (theta|phi; later y)
  short* gT   = (short*)(ws + 151003136);    // 33,554,432 B (4x1024x4096)
  short* sc   = (short*)(ws);                // 67,108,864 B (2x4096x4096, over xf)

  // 1) fp32 -> f16 conversions (x big pass + single merged weight pass)
  cvt_f32_f16<<<16384, 256, 0, stream>>>(x, xf, 33554432);
  cvt_weights<<<4096, 256, 0, stream>>>(thw, phw, gw, Ww, wcat, gwb, wWb, thb,
                                        phb, bc);

  // 2) proj: [theta|phi] = x @ wcat^T + bias   (16384 x 2048, K=2048)
  gemmph<4, 2048, 1, 1, 0><<<dim3(8, 64, 1), 512, 0, stream>>>(
      xf, 2048, 0L, wcat, 2048, 0L, tpf, 2048, 0L, bc, nullptr, 0L);

  // 3) gT[b] = g_w @ x_b^T + g_b[row]   (1024 x 4096 per batch, K=2048)
  gemmph<4, 2048, 1, 2, 0><<<dim3(16, 4, 4), 512, 0, stream>>>(
      gwb, 2048, 0L, xf, 2048, 8388608L, gT, 4096, 4194304L, gbi, nullptr, 0L);

  // 4) per batch-PAIR p: scores(z=2) -> softmax -> y(z=2) -> z(z=2)
  //    sc pair overlays xf (dead after gT); y overwrites consumed theta/phi.
  for (int p = 0; p < 2; ++p) {
    const short* tp = tpf + (size_t)p * 16777216;
    gemmph<4, 1024, 1, 0, 0><<<dim3(16, 16, 2), 512, 0, stream>>>(
        tp, 2048, 8388608L, tp + 1024, 2048, 8388608L,
        sc, 4096, 16777216L, nullptr, nullptr, 0L);
    softmax_rows<<<8192, 256, 0, stream>>>(sc);
    short* yp = tpf + (size_t)p * 16777216;  // pair-p theta/phi now dead
    gemmph<2, 4096, 1, 0, 0><<<dim3(8, 16, 2), 512, 0, stream>>>(
        sc, 4096, 16777216L, gT + (size_t)p * 8388608, 4096, 4194304L,
        yp, 1024, 4194304L, nullptr, nullptr, 0L);
    gemmph<4, 1024, 0, 1, 1><<<dim3(8, 16, 2), 512, 0, stream>>>(
        yp, 1024, 4194304L, wWb, 1024, 0L,
        out + (size_t)p * 16777216, 2048, 8388608L,
        Wb, x + (size_t)p * 16777216, 8388608L);
  }
}

// Round 17
// 662.029 us; speedup vs baseline: 1.2445x; 1.0583x over previous
//
#include <hip/hip_runtime.h>

typedef short bf16x8 __attribute__((ext_vector_type(8)));
typedef _Float16 f16x8 __attribute__((ext_vector_type(8)));
typedef float f32x4 __attribute__((ext_vector_type(4)));

__device__ __forceinline__ short f2h(float f) {
  _Float16 h = (_Float16)f;
  return __builtin_bit_cast(short, h);
}
__device__ __forceinline__ float h2f(short s) {
  return (float)__builtin_bit_cast(_Float16, s);
}

__device__ __forceinline__ void gload16(const void* g, void* lds) {
  __builtin_amdgcn_global_load_lds(
      (const __attribute__((address_space(1))) unsigned*)g,
      (__attribute__((address_space(3))) unsigned*)lds, 16, 0, 0);
}

// ---------------------------------------------------------------------------
// r6/r14 structure (best measured: 142 us proj, 0 bank conflicts) + T1
// XCD-aware block swizzle. Default dispatch round-robins consecutive wgs
// across the 8 XCD L2s, so the 8 blocks sharing one A-panel all cold-miss
// L3 simultaneously -> proj FETCH 270 MB vs 75 ideal. Swizzle
// swz=(wg&7)*(nwg/8)+wg/8 gives each XCD a contiguous by-run: A-panels
// become XCD-exclusive, B-panels L3-served. All grids have nwg%8==0.
// ---------------------------------------------------------------------------
template <int NF, int K, int OMODE, int BIAS_MODE, int RES>
__global__ __launch_bounds__(512, 2) void gemm256(
    const short* __restrict__ A, int lda, long sA,
    const short* __restrict__ B, int ldb, long sB,
    void* __restrict__ Cv, int ldc, long sC,
    const float* __restrict__ bias, const float* __restrict__ resid, long sR) {
  constexpr int BN = NF * 64;
  constexpr int BNB = BN * 128;  // B-tile bytes per buffer
  constexpr int NT = K / 64;
  __shared__ char lds[65536 + 2 * BNB];  // A: 2x32KB, B: 2xBNB

  A += (size_t)blockIdx.z * sA;
  B += (size_t)blockIdx.z * sB;
  char* Cb = (char*)Cv + (size_t)blockIdx.z * sC * (OMODE == 0 ? 4 : 2);
  const float* res = resid ? resid + (size_t)blockIdx.z * sR : nullptr;

  // T1 XCD swizzle (nwg % 8 == 0 for every launch below)
  const int nwg = gridDim.x * gridDim.y;
  const int wg = blockIdx.x + gridDim.x * blockIdx.y;
  const int swzid = (wg & 7) * (nwg >> 3) + (wg >> 3);
  const int bxi = swzid % gridDim.x, byi = swzid / gridDim.x;

  const int tid = threadIdx.x;
  const int wid = tid >> 6, lane = tid & 63;
  const int wr = wid >> 2, wc = wid & 3;  // wave grid 2 (M) x 4 (N)
  const int fr = lane & 15, fq = lane >> 4;
  const size_t bm = (size_t)byi * 256;
  const size_t bn = (size_t)bxi * BN;

  // staging: per chunk 64 rows x 128 B; thread covers row srow, 16 B at scolS
  const int srow = wid * 8 + (lane >> 3);                   // 0..63
  const int scolS = ((lane & 7) * 16) ^ ((srow & 7) << 4);  // inv-swizzled src
  const char* Ag = (const char*)A;
  const char* Bg = (const char*)B;

  // ds_read byte offsets (ks=0, buffer 0); row&7 == fr&7 for all fragments
  const int swz = (fr & 7) << 4;
  int aoff[8], boff[NF];
#pragma unroll
  for (int m = 0; m < 8; m++)
    aoff[m] = (wr * 128 + m * 16 + fr) * 128 + ((fq * 16) ^ swz);
#pragma unroll
  for (int n = 0; n < NF; n++)
    boff[n] = (wc * NF * 16 + n * 16 + fr) * 128 + ((fq * 16) ^ swz);

  f32x4 acc[8][NF];
#pragma unroll
  for (int m = 0; m < 8; m++)
#pragma unroll
    for (int n = 0; n < NF; n++) acc[m][n] = (f32x4){0.f, 0.f, 0.f, 0.f};

  auto stage = [&](int t, int d) {
    const int ktb = t * 128;  // byte offset along K
#pragma unroll
    for (int c = 0; c < 4; ++c)
      gload16(Ag + ((size_t)(bm + c * 64 + srow) * lda) * 2 + ktb + scolS,
              &lds[d * 32768 + c * 8192 + wid * 1024]);
#pragma unroll
    for (int c = 0; c < NF; ++c)
      gload16(Bg + ((size_t)(bn + c * 64 + srow) * ldb) * 2 + ktb + scolS,
              &lds[65536 + d * BNB + c * 8192 + wid * 1024]);
  };

  stage(0, 0);
  int cur = 0;
#pragma unroll 2
  for (int t = 0; t < NT; ++t) {
    if (t + 1 < NT) stage(t + 1, cur ^ 1);
    __builtin_amdgcn_sched_barrier(0);
    if (t + 1 < NT) {
      if constexpr (NF == 4)
        asm volatile("s_waitcnt vmcnt(8)");  // tile t done; t+1's 8 in flight
      else
        asm volatile("s_waitcnt vmcnt(6)");
    } else {
      asm volatile("s_waitcnt vmcnt(0)");
    }
    __builtin_amdgcn_sched_barrier(0);
    __builtin_amdgcn_s_barrier();  // all waves see buf[cur] full
    __builtin_amdgcn_sched_barrier(0);
    {
      const int dA = cur * 32768, dB = 65536 + cur * BNB;
#pragma unroll
      for (int ks = 0; ks < 2; ++ks) {
        f16x8 ar[8], br[NF];
#pragma unroll
        for (int m = 0; m < 8; m++)
          ar[m] = *(const f16x8*)&lds[dA + (aoff[m] ^ (ks << 6))];
#pragma unroll
        for (int n = 0; n < NF; n++)
          br[n] = *(const f16x8*)&lds[dB + (boff[n] ^ (ks << 6))];
#pragma unroll
        for (int m = 0; m < 8; m++)
#pragma unroll
          for (int n = 0; n < NF; n++)
            acc[m][n] = __builtin_amdgcn_mfma_f32_16x16x32_f16(
                ar[m], br[n], acc[m][n], 0, 0, 0);
      }
    }
    __builtin_amdgcn_sched_barrier(0);
    __builtin_amdgcn_s_barrier();  // buf[cur] free for overwrite next iter
    __builtin_amdgcn_sched_barrier(0);
    cur ^= 1;
  }

#pragma unroll
  for (int m = 0; m < 8; m++) {
    const size_t row0 = bm + wr * 128 + m * 16 + fq * 4;
#pragma unroll
    for (int n = 0; n < NF; n++) {
      const size_t col = bn + wc * NF * 16 + n * 16 + fr;
      float bcol = (BIAS_MODE == 1) ? bias[col] : 0.f;
#pragma unroll
      for (int r = 0; r < 4; r++) {
        float val = acc[m][n][r];
        const size_t row = row0 + r;
        const size_t idx = row * (size_t)ldc + col;
        if (BIAS_MODE == 1) val += bcol;
        if (BIAS_MODE == 2) val += bias[row];
        if (RES) val += res[idx];
        if (OMODE == 0)
          ((float*)Cb)[idx] = val;
        else
          ((short*)Cb)[idx] = f2h(val);
      }
    }
  }
}

__global__ __launch_bounds__(256) void cvt_f32_f16(const float* __restrict__ s,
                                                   short* __restrict__ d, int n) {
  int i = (blockIdx.x * 256 + threadIdx.x) * 8;
  if (i >= n) return;
  const float4 a = *(const float4*)(s + i);
  const float4 b = *(const float4*)(s + i + 4);
  bf16x8 o;
  o[0] = f2h(a.x); o[1] = f2h(a.y); o[2] = f2h(a.z); o[3] = f2h(a.w);
  o[4] = f2h(b.x); o[5] = f2h(b.y); o[6] = f2h(b.z); o[7] = f2h(b.w);
  *(bf16x8*)(d + i) = o;
}

// merged weight conversion: 4 x (2M f32 -> f16) + theta_b|phi_b bias concat.
__global__ __launch_bounds__(256) void cvt_weights(
    const float* __restrict__ thw, const float* __restrict__ phw,
    const float* __restrict__ gw, const float* __restrict__ Ww,
    short* __restrict__ wcat, short* __restrict__ gwb, short* __restrict__ wWb,
    const float* __restrict__ thb, const float* __restrict__ phb,
    float* __restrict__ bc) {
  const int b = blockIdx.x;  // 0..4095
  const int seg = b >> 10, ib = b & 1023;
  const float* s;
  short* d;
  if (seg == 0) { s = thw; d = wcat; }
  else if (seg == 1) { s = phw; d = wcat + 2097152; }
  else if (seg == 2) { s = gw; d = gwb; }
  else { s = Ww; d = wWb; }
  const int i = (ib * 256 + threadIdx.x) * 8;
  const float4 a = *(const float4*)(s + i);
  const float4 v = *(const float4*)(s + i + 4);
  bf16x8 o;
  o[0] = f2h(a.x); o[1] = f2h(a.y); o[2] = f2h(a.z); o[3] = f2h(a.w);
  o[4] = f2h(v.x); o[5] = f2h(v.y); o[6] = f2h(v.z); o[7] = f2h(v.w);
  *(bf16x8*)(d + i) = o;
  if (b == 0) {  // bias concat: 256 thr x 8 f32 = 2048
    const int j = threadIdx.x * 8;
#pragma unroll
    for (int k = 0; k < 8; ++k) {
      const int jj = j + k;
      bc[jj] = (jj < 1024) ? thb[jj] : phb[jj - 1024];
    }
  }
}

// one block per row of 4096 f16 scores; fp32 softmax; in-place f16 probs
__global__ __launch_bounds__(256) void softmax_rows(short* __restrict__ S) {
  const size_t row = blockIdx.x;
  short* rp = S + row * 4096;
  const int tid = threadIdx.x;
  const int lane = tid & 63, wid = tid >> 6;
  float v[16];
#pragma unroll
  for (int c = 0; c < 2; c++) {
    bf16x8 xv = *(const bf16x8*)(rp + (c * 256 + tid) * 8);
#pragma unroll
    for (int j = 0; j < 8; j++) v[c * 8 + j] = h2f(xv[j]);
  }
  float m = v[0];
#pragma unroll
  for (int i = 1; i < 16; i++) m = fmaxf(m, v[i]);
#pragma unroll
  for (int off = 32; off >= 1; off >>= 1) m = fmaxf(m, __shfl_xor(m, off));
  __shared__ float red[8];
  if (lane == 0) red[wid] = m;
  __syncthreads();
  m = fmaxf(fmaxf(red[0], red[1]), fmaxf(red[2], red[3]));
  float s = 0.f;
#pragma unroll
  for (int i = 0; i < 16; i++) {
    v[i] = __expf(v[i] - m);
    s += v[i];
  }
#pragma unroll
  for (int off = 32; off >= 1; off >>= 1) s += __shfl_xor(s, off);
  if (lane == 0) red[4 + wid] = s;
  __syncthreads();
  s = (red[4] + red[5]) + (red[6] + red[7]);
  const float rs = 1.0f / s;
#pragma unroll
  for (int c = 0; c < 2; c++) {
    bf16x8 o;
#pragma unroll
    for (int j = 0; j < 8; j++) o[j] = f2h(v[c * 8 + j] * rs);
    *(bf16x8*)(rp + (c * 256 + tid) * 8) = o;
  }
}

extern "C" void kernel_launch(void* const* d_in, const int* in_sizes, int n_in,
                              void* d_out, int out_size, void* d_ws,
                              size_t ws_size, hipStream_t stream) {
  const float* x   = (const float*)d_in[0];
  const float* thw = (const float*)d_in[1];
  const float* thb = (const float*)d_in[2];
  const float* phw = (const float*)d_in[3];
  const float* phb = (const float*)d_in[4];
  const float* gw  = (const float*)d_in[5];
  const float* gbi = (const float*)d_in[6];
  const float* Ww  = (const float*)d_in[7];
  const float* Wb  = (const float*)d_in[8];
  float* out = (float*)d_out;

  // B=4, N=4096, D=2048, E=1024.  ws footprint 184,557,568 B (proven size)
  char* ws = (char*)d_ws;
  short* xf   = (short*)(ws);                // 67,108,864 B (16384x2048 f16)
  short* wcat = (short*)(ws + 67108864);     //  8,388,608 B (theta|phi 2048x2048)
  short* gwb  = (short*)(ws + 75497472);     //  4,194,304 B (1024x2048)
  short* wWb  = (short*)(ws + 79691776);     //  4,194,304 B (2048x1024)
  float* bc   = (float*)(ws + 83886080);     //  8,192 B (theta_b|phi_b)
  short* tpf  = (short*)(ws + 83894272);     // 67,108,864 B (theta|phi; later y)
  short* gT   = (short*)(ws + 151003136);    // 33,554,432 B (4x1024x4096)
  short* sc   = (short*)(ws);                // 67,108,864 B (2x4096x4096, over xf)

  // 1) fp32 -> f16 conversions (x big pass + single merged weight pass)
  cvt_f32_f16<<<16384, 256, 0, stream>>>(x, xf, 33554432);
  cvt_weights<<<4096, 256, 0, stream>>>(thw, phw, gw, Ww, wcat, gwb, wWb, thb,
                                        phb, bc);

  // 2) proj: [theta|phi] = x @ wcat^T + bias   (16384 x 2048, K=2048)
  gemm256<4, 2048, 1, 1, 0><<<dim3(8, 64, 1), 512, 0, stream>>>(
      xf, 2048, 0L, wcat, 2048, 0L, tpf, 2048, 0L, bc, nullptr, 0L);

  // 3) gT[b] = g_w @ x_b^T + g_b[row]   (1024 x 4096 per batch, K=2048)
  gemm256<4, 2048, 1, 2, 0><<<dim3(16, 4, 4), 512, 0, stream>>>(
      gwb, 2048, 0L, xf, 2048, 8388608L, gT, 4096, 4194304L, gbi, nullptr, 0L);

  // 4) per batch-PAIR p: scores(z=2) -> softmax -> y(z=2) -> z(z=2)
  //    sc pair overlays xf (dead after gT); y overwrites consumed theta/phi.
  for (int p = 0; p < 2; ++p) {
    const short* tp = tpf + (size_t)p * 16777216;
    gemm256<4, 1024, 1, 0, 0><<<dim3(16, 16, 2), 512, 0, stream>>>(
        tp, 2048, 8388608L, tp + 1024, 2048, 8388608L,
        sc, 4096, 16777216L, nullptr, nullptr, 0L);
    softmax_rows<<<8192, 256, 0, stream>>>(sc);
    short* yp = tpf + (size_t)p * 16777216;  // pair-p theta/phi now dead
    gemm256<2, 4096, 1, 0, 0><<<dim3(8, 16, 2), 512, 0, stream>>>(
        sc, 4096, 16777216L, gT + (size_t)p * 8388608, 4096, 4194304L,
        yp, 1024, 4194304L, nullptr, nullptr, 0L);
    gemm256<4, 1024, 0, 1, 1><<<dim3(8, 16, 2), 512, 0, stream>>>(
        yp, 1024, 4194304L, wWb, 1024, 0L,
        out + (size_t)p * 16777216, 2048, 8388608L,
        Wb, x + (size_t)p * 16777216, 8388608L);
  }
}

// Round 18
// 661.152 us; speedup vs baseline: 1.2461x; 1.0013x over previous
//
#include <hip/hip_runtime.h>

typedef short bf16x8 __attribute__((ext_vector_type(8)));
typedef _Float16 f16x8 __attribute__((ext_vector_type(8)));
typedef float f32x4 __attribute__((ext_vector_type(4)));

__device__ __forceinline__ short f2h(float f) {
  _Float16 h = (_Float16)f;
  return __builtin_bit_cast(short, h);
}
__device__ __forceinline__ float h2f(short s) {
  return (float)__builtin_bit_cast(_Float16, s);
}

__device__ __forceinline__ void gload16(const void* g, void* lds) {
  __builtin_amdgcn_global_load_lds(
      (const __attribute__((address_space(1))) unsigned*)g,
      (__attribute__((address_space(3))) unsigned*)lds, 16, 0, 0);
}

// ---------------------------------------------------------------------------
// r6/r14 structure (142 us proj, 0 bank conflicts) + T1 XCD swizzle (r17:
// FETCH 270->100 MB, -38 us total). RES=1: fp32 residual; RES=2: f16
// residual (halves z-GEMM residual HBM traffic; rounding delta ~1e-3).
// ---------------------------------------------------------------------------
template <int NF, int K, int OMODE, int BIAS_MODE, int RES>
__global__ __launch_bounds__(512, 2) void gemm256(
    const short* __restrict__ A, int lda, long sA,
    const short* __restrict__ B, int ldb, long sB,
    void* __restrict__ Cv, int ldc, long sC,
    const float* __restrict__ bias, const void* __restrict__ resid, long sR) {
  constexpr int BN = NF * 64;
  constexpr int BNB = BN * 128;  // B-tile bytes per buffer
  constexpr int NT = K / 64;
  __shared__ char lds[65536 + 2 * BNB];  // A: 2x32KB, B: 2xBNB

  A += (size_t)blockIdx.z * sA;
  B += (size_t)blockIdx.z * sB;
  char* Cb = (char*)Cv + (size_t)blockIdx.z * sC * (OMODE == 0 ? 4 : 2);
  const float* resf = nullptr;
  const short* resh = nullptr;
  if (RES == 1) resf = (const float*)resid + (size_t)blockIdx.z * sR;
  if (RES == 2) resh = (const short*)resid + (size_t)blockIdx.z * sR;

  // T1 XCD swizzle (nwg % 8 == 0 for every launch below)
  const int nwg = gridDim.x * gridDim.y;
  const int wg = blockIdx.x + gridDim.x * blockIdx.y;
  const int swzid = (wg & 7) * (nwg >> 3) + (wg >> 3);
  const int bxi = swzid % gridDim.x, byi = swzid / gridDim.x;

  const int tid = threadIdx.x;
  const int wid = tid >> 6, lane = tid & 63;
  const int wr = wid >> 2, wc = wid & 3;  // wave grid 2 (M) x 4 (N)
  const int fr = lane & 15, fq = lane >> 4;
  const size_t bm = (size_t)byi * 256;
  const size_t bn = (size_t)bxi * BN;

  // staging: per chunk 64 rows x 128 B; thread covers row srow, 16 B at scolS
  const int srow = wid * 8 + (lane >> 3);                   // 0..63
  const int scolS = ((lane & 7) * 16) ^ ((srow & 7) << 4);  // inv-swizzled src
  const char* Ag = (const char*)A;
  const char* Bg = (const char*)B;

  // ds_read byte offsets (ks=0, buffer 0); row&7 == fr&7 for all fragments
  const int swz = (fr & 7) << 4;
  int aoff[8], boff[NF];
#pragma unroll
  for (int m = 0; m < 8; m++)
    aoff[m] = (wr * 128 + m * 16 + fr) * 128 + ((fq * 16) ^ swz);
#pragma unroll
  for (int n = 0; n < NF; n++)
    boff[n] = (wc * NF * 16 + n * 16 + fr) * 128 + ((fq * 16) ^ swz);

  f32x4 acc[8][NF];
#pragma unroll
  for (int m = 0; m < 8; m++)
#pragma unroll
    for (int n = 0; n < NF; n++) acc[m][n] = (f32x4){0.f, 0.f, 0.f, 0.f};

  auto stage = [&](int t, int d) {
    const int ktb = t * 128;  // byte offset along K
#pragma unroll
    for (int c = 0; c < 4; ++c)
      gload16(Ag + ((size_t)(bm + c * 64 + srow) * lda) * 2 + ktb + scolS,
              &lds[d * 32768 + c * 8192 + wid * 1024]);
#pragma unroll
    for (int c = 0; c < NF; ++c)
      gload16(Bg + ((size_t)(bn + c * 64 + srow) * ldb) * 2 + ktb + scolS,
              &lds[65536 + d * BNB + c * 8192 + wid * 1024]);
  };

  stage(0, 0);
  int cur = 0;
#pragma unroll 2
  for (int t = 0; t < NT; ++t) {
    if (t + 1 < NT) stage(t + 1, cur ^ 1);
    __builtin_amdgcn_sched_barrier(0);
    if (t + 1 < NT) {
      if constexpr (NF == 4)
        asm volatile("s_waitcnt vmcnt(8)");  // tile t done; t+1's 8 in flight
      else
        asm volatile("s_waitcnt vmcnt(6)");
    } else {
      asm volatile("s_waitcnt vmcnt(0)");
    }
    __builtin_amdgcn_sched_barrier(0);
    __builtin_amdgcn_s_barrier();  // all waves see buf[cur] full
    __builtin_amdgcn_sched_barrier(0);
    {
      const int dA = cur * 32768, dB = 65536 + cur * BNB;
#pragma unroll
      for (int ks = 0; ks < 2; ++ks) {
        f16x8 ar[8], br[NF];
#pragma unroll
        for (int m = 0; m < 8; m++)
          ar[m] = *(const f16x8*)&lds[dA + (aoff[m] ^ (ks << 6))];
#pragma unroll
        for (int n = 0; n < NF; n++)
          br[n] = *(const f16x8*)&lds[dB + (boff[n] ^ (ks << 6))];
#pragma unroll
        for (int m = 0; m < 8; m++)
#pragma unroll
          for (int n = 0; n < NF; n++)
            acc[m][n] = __builtin_amdgcn_mfma_f32_16x16x32_f16(
                ar[m], br[n], acc[m][n], 0, 0, 0);
      }
    }
    __builtin_amdgcn_sched_barrier(0);
    __builtin_amdgcn_s_barrier();  // buf[cur] free for overwrite next iter
    __builtin_amdgcn_sched_barrier(0);
    cur ^= 1;
  }

#pragma unroll
  for (int m = 0; m < 8; m++) {
    const size_t row0 = bm + wr * 128 + m * 16 + fq * 4;
#pragma unroll
    for (int n = 0; n < NF; n++) {
      const size_t col = bn + wc * NF * 16 + n * 16 + fr;
      float bcol = (BIAS_MODE == 1) ? bias[col] : 0.f;
#pragma unroll
      for (int r = 0; r < 4; r++) {
        float val = acc[m][n][r];
        const size_t row = row0 + r;
        const size_t idx = row * (size_t)ldc + col;
        if (BIAS_MODE == 1) val += bcol;
        if (BIAS_MODE == 2) val += bias[row];
        if (RES == 1) val += resf[idx];
        if (RES == 2) val += h2f(resh[idx]);
        if (OMODE == 0)
          ((float*)Cb)[idx] = val;
        else
          ((short*)Cb)[idx] = f2h(val);
      }
    }
  }
}

__global__ __launch_bounds__(256) void cvt_f32_f16(const float* __restrict__ s,
                                                   short* __restrict__ d, int n) {
  int i = (blockIdx.x * 256 + threadIdx.x) * 8;
  if (i >= n) return;
  const float4 a = *(const float4*)(s + i);
  const float4 b = *(const float4*)(s + i + 4);
  bf16x8 o;
  o[0] = f2h(a.x); o[1] = f2h(a.y); o[2] = f2h(a.z); o[3] = f2h(a.w);
  o[4] = f2h(b.x); o[5] = f2h(b.y); o[6] = f2h(b.z); o[7] = f2h(b.w);
  *(bf16x8*)(d + i) = o;
}

// merged weight conversion: 4 x (2M f32 -> f16) + theta_b|phi_b bias concat.
__global__ __launch_bounds__(256) void cvt_weights(
    const float* __restrict__ thw, const float* __restrict__ phw,
    const float* __restrict__ gw, const float* __restrict__ Ww,
    short* __restrict__ wcat, short* __restrict__ gwb, short* __restrict__ wWb,
    const float* __restrict__ thb, const float* __restrict__ phb,
    float* __restrict__ bc) {
  const int b = blockIdx.x;  // 0..4095
  const int seg = b >> 10, ib = b & 1023;
  const float* s;
  short* d;
  if (seg == 0) { s = thw; d = wcat; }
  else if (seg == 1) { s = phw; d = wcat + 2097152; }
  else if (seg == 2) { s = gw; d = gwb; }
  else { s = Ww; d = wWb; }
  const int i = (ib * 256 + threadIdx.x) * 8;
  const float4 a = *(const float4*)(s + i);
  const float4 v = *(const float4*)(s + i + 4);
  bf16x8 o;
  o[0] = f2h(a.x); o[1] = f2h(a.y); o[2] = f2h(a.z); o[3] = f2h(a.w);
  o[4] = f2h(v.x); o[5] = f2h(v.y); o[6] = f2h(v.z); o[7] = f2h(v.w);
  *(bf16x8*)(d + i) = o;
  if (b == 0) {  // bias concat: 256 thr x 8 f32 = 2048
    const int j = threadIdx.x * 8;
#pragma unroll
    for (int k = 0; k < 8; ++k) {
      const int jj = j + k;
      bc[jj] = (jj < 1024) ? thb[jj] : phb[jj - 1024];
    }
  }
}

// one block per row of 4096 f16 scores; fp32 softmax; in-place f16 probs
__global__ __launch_bounds__(256) void softmax_rows(short* __restrict__ S) {
  const size_t row = blockIdx.x;
  short* rp = S + row * 4096;
  const int tid = threadIdx.x;
  const int lane = tid & 63, wid = tid >> 6;
  float v[16];
#pragma unroll
  for (int c = 0; c < 2; c++) {
    bf16x8 xv = *(const bf16x8*)(rp + (c * 256 + tid) * 8);
#pragma unroll
    for (int j = 0; j < 8; j++) v[c * 8 + j] = h2f(xv[j]);
  }
  float m = v[0];
#pragma unroll
  for (int i = 1; i < 16; i++) m = fmaxf(m, v[i]);
#pragma unroll
  for (int off = 32; off >= 1; off >>= 1) m = fmaxf(m, __shfl_xor(m, off));
  __shared__ float red[8];
  if (lane == 0) red[wid] = m;
  __syncthreads();
  m = fmaxf(fmaxf(red[0], red[1]), fmaxf(red[2], red[3]));
  float s = 0.f;
#pragma unroll
  for (int i = 0; i < 16; i++) {
    v[i] = __expf(v[i] - m);
    s += v[i];
  }
#pragma unroll
  for (int off = 32; off >= 1; off >>= 1) s += __shfl_xor(s, off);
  if (lane == 0) red[4 + wid] = s;
  __syncthreads();
  s = (red[4] + red[5]) + (red[6] + red[7]);
  const float rs = 1.0f / s;
#pragma unroll
  for (int c = 0; c < 2; c++) {
    bf16x8 o;
#pragma unroll
    for (int j = 0; j < 8; j++) o[j] = f2h(v[c * 8 + j] * rs);
    *(bf16x8*)(rp + (c * 256 + tid) * 8) = o;
  }
}

extern "C" void kernel_launch(void* const* d_in, const int* in_sizes, int n_in,
                              void* d_out, int out_size, void* d_ws,
                              size_t ws_size, hipStream_t stream) {
  const float* x   = (const float*)d_in[0];
  const float* thw = (const float*)d_in[1];
  const float* thb = (const float*)d_in[2];
  const float* phw = (const float*)d_in[3];
  const float* phb = (const float*)d_in[4];
  const float* gw  = (const float*)d_in[5];
  const float* gbi = (const float*)d_in[6];
  const float* Ww  = (const float*)d_in[7];
  const float* Wb  = (const float*)d_in[8];
  float* out = (float*)d_out;

  // B=4, N=4096, D=2048, E=1024.  ws footprint 184,557,568 B (proven size)
  char* ws = (char*)d_ws;
  short* xf   = (short*)(ws);                // 67,108,864 B (16384x2048 f16)
  short* wcat = (short*)(ws + 67108864);     //  8,388,608 B (theta|phi 2048x2048)
  short* gwb  = (short*)(ws + 75497472);     //  4,194,304 B (1024x2048)
  short* wWb  = (short*)(ws + 79691776);     //  4,194,304 B (2048x1024)
  float* bc   = (float*)(ws + 83886080);     //  8,192 B (theta_b|phi_b)
  short* tpf  = (short*)(ws + 83894272);     // 67,108,864 B (theta|phi; later y)
  short* gT   = (short*)(ws + 151003136);    // 33,554,432 B (4x1024x4096)
  short* sc   = (short*)(ws);                // 67,108,864 B (2x4096x4096, over xf)
  // NOTE: sc overlays xf[0 .. 33.5MB*2]; z-GEMM's f16 residual reads xf — but
  // sc only overwrites the first pair's region while xf rows for residual are
  // re-read per pair... xf IS clobbered by sc. Use the UNTOUCHED upper copy:
  // sc occupies ws[0..67MB) which is exactly xf. So residual must NOT read xf.
  // Instead keep residual fp32 for pair regions whose xf is dead, and f16 is
  // only safe if sourced elsewhere. Solution: stage z residual from xf BEFORE
  // sc overwrite is impossible; so z reads a dedicated f16 copy xr kept in the
  // gT tail region? gT is live. Fall back: pair-p z reads xf only when p==...
  // SAFE CHOICE: z residual reads x (fp32) for pair 0 (its sc overlay is
  // live) and xf is already clobbered -> use fp32 for both. To still save
  // traffic, z for pair p runs BEFORE pair p+1's scores overwrite? Ordering:
  // sc (pair p) overwrites xf rows [0..8192) always (same region both pairs).
  // xf rows needed by z pair p = rows [p*8192..(p+1)*8192). Pair 1's z can
  // safely read xf rows 8192..16384 (sc never touches ws beyond 67MB? sc =
  // ws[0..67MB) = ALL of xf). sc pair covers 2x4096x4096 f16 = 67MB = all xf.
  // -> f16 residual is unsafe; keep RES=1 (fp32) for z. (Documented dead end;
  // launch below uses RES=1.)

  // 1) fp32 -> f16 conversions (x big pass + single merged weight pass)
  cvt_f32_f16<<<16384, 256, 0, stream>>>(x, xf, 33554432);
  cvt_weights<<<4096, 256, 0, stream>>>(thw, phw, gw, Ww, wcat, gwb, wWb, thb,
                                        phb, bc);

  // 2) proj: [theta|phi] = x @ wcat^T + bias   (16384 x 2048, K=2048)
  gemm256<4, 2048, 1, 1, 0><<<dim3(8, 64, 1), 512, 0, stream>>>(
      xf, 2048, 0L, wcat, 2048, 0L, tpf, 2048, 0L, bc, nullptr, 0L);

  // 3) gT[b] = g_w @ x_b^T + g_b[row]   (1024 x 4096 per batch, K=2048)
  gemm256<4, 2048, 1, 2, 0><<<dim3(16, 4, 4), 512, 0, stream>>>(
      gwb, 2048, 0L, xf, 2048, 8388608L, gT, 4096, 4194304L, gbi, nullptr, 0L);

  // 4) per batch-PAIR p: scores(z=2) -> softmax -> y(z=2) -> z(z=2)
  //    sc pair overlays xf (dead after gT); y overwrites consumed theta/phi.
  for (int p = 0; p < 2; ++p) {
    const short* tp = tpf + (size_t)p * 16777216;
    gemm256<4, 1024, 1, 0, 0><<<dim3(16, 16, 2), 512, 0, stream>>>(
        tp, 2048, 8388608L, tp + 1024, 2048, 8388608L,
        sc, 4096, 16777216L, nullptr, nullptr, 0L);
    softmax_rows<<<8192, 256, 0, stream>>>(sc);
    short* yp = tpf + (size_t)p * 16777216;  // pair-p theta/phi now dead
    gemm256<2, 4096, 1, 0, 0><<<dim3(8, 16, 2), 512, 0, stream>>>(
        sc, 4096, 16777216L, gT + (size_t)p * 8388608, 4096, 4194304L,
        yp, 1024, 4194304L, nullptr, nullptr, 0L);
    gemm256<4, 1024, 0, 1, 1><<<dim3(8, 16, 2), 512, 0, stream>>>(
        yp, 1024, 4194304L, wWb, 1024, 0L,
        out + (size_t)p * 16777216, 2048, 8388608L,
        Wb, x + (size_t)p * 16777216, 8388608L);
  }
}